// Round 6
// baseline (355.875 us; speedup 1.0000x reference)
//
#include <hip/hip_runtime.h>
#include <cstdint>

#define L_ 4096
#define NC_ 512
#define CD_ 256
#define H_ 8
#define D_ 128
#define B_ 4
#define SCALE 0.08838834764831845f
#define TAU 3.0e-3f

typedef _Float16 f16x8 __attribute__((ext_vector_type(8)));
typedef _Float16 f16x4 __attribute__((ext_vector_type(4)));
typedef float f32x16 __attribute__((ext_vector_type(16)));
typedef float f32x4 __attribute__((ext_vector_type(4)));

// ---------------------------------------------------------------------------
// Kernel A (verbatim, verified): K16f fp16 fragment-major, K32/V fp32 row-major.
// ---------------------------------------------------------------------------
__global__ __launch_bounds__(256) void kv_pre(
    const float* __restrict__ codes, const float* __restrict__ Wk,
    const float* __restrict__ Wv, _Float16* __restrict__ K16f,
    float* __restrict__ K32, float* __restrict__ V)
{
    __shared__ float clds[8][256];
    const int t = threadIdx.x, h = blockIdx.y, n0 = blockIdx.x * 8;
    {
        const float4* cs = (const float4*)(codes + (size_t)n0 * CD_);
        float4* cd = (float4*)&clds[0][0];
        cd[t] = cs[t]; cd[t + 256] = cs[t + 256];
    }
    __syncthreads();
    const int nl = t >> 5, dq = t & 31, d0 = dq * 4, n = n0 + nl;
    float ak0=0,ak1=0,ak2=0,ak3=0, av0=0,av1=0,av2=0,av3=0;
    const float4* wk4 = (const float4*)Wk;
    const float4* wv4 = (const float4*)Wv;
    for (int c = 0; c < CD_; c += 4) {
        float4 cv = *(const float4*)&clds[nl][c];
        #pragma unroll
        for (int u = 0; u < 4; ++u) {
            float cu = (u==0)?cv.x:(u==1)?cv.y:(u==2)?cv.z:cv.w;
            float4 wk = wk4[((size_t)(c+u)*H_ + h)*32 + dq];
            float4 wv = wv4[((size_t)(c+u)*H_ + h)*32 + dq];
            ak0 = fmaf(cu, wk.x, ak0); ak1 = fmaf(cu, wk.y, ak1);
            ak2 = fmaf(cu, wk.z, ak2); ak3 = fmaf(cu, wk.w, ak3);
            av0 = fmaf(cu, wv.x, av0); av1 = fmaf(cu, wv.y, av1);
            av2 = fmaf(cu, wv.z, av2); av3 = fmaf(cu, wv.w, av3);
        }
    }
    const size_t r32 = ((size_t)(h*NC_ + n))*D_ + d0;
    float4 sk; sk.x=ak0; sk.y=ak1; sk.z=ak2; sk.w=ak3;
    float4 sv; sv.x=av0; sv.y=av1; sv.z=av2; sv.w=av3;
    *(float4*)(K32 + r32) = sk;
    *(float4*)(V   + r32) = sv;
    f16x4 hk; hk[0]=(_Float16)ak0; hk[1]=(_Float16)ak1; hk[2]=(_Float16)ak2; hk[3]=(_Float16)ak3;
    const size_t a16 = ((size_t)((h*16 + (n>>5))*8 + (d0>>4))*64
                        + ((n&31) + ((d0>>3)&1)*32))*8 + (d0&7);
    *(f16x4*)(K16f + a16) = hk;
}

// ---------------------------------------------------------------------------
// Shared machinery (round-5 verified)
// ---------------------------------------------------------------------------
#define GLD_LDS16(GP, LP)                                                      \
  __builtin_amdgcn_global_load_lds(                                            \
      (const __attribute__((address_space(1))) void*)(GP),                     \
      (__attribute__((address_space(3))) void*)(LP), 16, 0, 0)

#define WAIT_VM(N)  asm volatile("s_waitcnt vmcnt(" #N ")" ::: "memory")
#define WAIT_LGKM   asm volatile("s_waitcnt lgkmcnt(0)" ::: "memory")

#define DECODE_IDS()                                                           \
    const int t = threadIdx.x;                                                 \
    const int wid = t >> 6, lane = t & 63;                                     \
    const int bid = blockIdx.x;                                                \
    const int h  = bid & 7;                                                    \
    const int rr_ = bid >> 3;                                                  \
    const int lx = rr_ & 31, b = rr_ >> 5;                                     \
    const int l0w = lx * 128 + wid * 32;                                       \
    const float* xb = x + ((size_t)(b*1024 + h*128)) * L_;                     \
    const int colL = lane & 31;                                                \
    const int hi = lane >> 5;                                                  \
    const int laneN4 = hi * 4;                                                 \
    (void)laneN4; (void)xb;

#define QSTAGE(RD, QS)                                                         \
  _Pragma("unroll")                                                            \
  for (int i_ = 0; i_ < 4; ++i_) {                                             \
    const float* sp_ = xb + (size_t)((RD)*32 + i_*8 + (lane>>3))*L_            \
                          + l0w + (lane&7)*4;                                  \
    GLD_LDS16(sp_, (char*)(QS) + i_*1024);                                     \
  }

#define QREAD(RD, QS)                                                          \
  _Pragma("unroll")                                                            \
  for (int p_ = 0; p_ < 2; ++p_) {                                             \
    f16x8 tmp_;                                                                \
    _Pragma("unroll")                                                          \
    for (int j_ = 0; j_ < 8; ++j_)                                             \
      tmp_[j_] = (_Float16)(SCALE * (QS)[(p_*16 + hi*8 + j_)*32 + colL]);      \
    qf[(RD)*2 + p_] = tmp_;                                                    \
  }

// builds one fragment (p half) into a named variable
#define QREAD1(RD, QS, P, DST)                                                 \
  {                                                                            \
    f16x8 tmp_;                                                                \
    _Pragma("unroll")                                                          \
    for (int j_ = 0; j_ < 8; ++j_)                                             \
      tmp_[j_] = (_Float16)(SCALE * (QS)[((P)*16 + hi*8 + j_)*32 + colL]);     \
    DST = tmp_;                                                                \
  }

#define QPHASE_ARR()                                                           \
    float* qs0 = (float*)(smem + wid * 8192);                                  \
    float* qs1 = (float*)(smem + wid * 8192 + 4096);                           \
    QSTAGE(0, qs0)                                                             \
    QSTAGE(1, qs1)                                                             \
    WAIT_VM(4); QREAD(0, qs0)                                                  \
    WAIT_LGKM;  QSTAGE(2, qs0)                                                 \
    WAIT_VM(4); QREAD(1, qs1)                                                  \
    WAIT_LGKM;  QSTAGE(3, qs1)                                                 \
    WAIT_VM(4); QREAD(2, qs0)                                                  \
    WAIT_VM(0); QREAD(3, qs1)

#define TOP2_UPDATE(ACC, NT)                                                   \
    {                                                                          \
      const int nb_ = (NT)*32 + laneN4;                                        \
      _Pragma("unroll")                                                        \
      for (int r = 0; r < 16; ++r) {                                           \
        const int n = nb_ + (r & 3) + ((r >> 2) << 3);                         \
        float v = (ACC)[r];                                                    \
        bool g = v > v1;                                                       \
        v2 = fmaxf(v2, fminf(v1, v));                                          \
        v1 = fmaxf(v1, v);                                                     \
        i1 = g ? n : i1;                                                       \
      }                                                                        \
    }

#define KLOOP_ARR()                                                            \
    GLD_LDS16(kh + (size_t)(wid*64 + lane)*8,       kbuf0 + (size_t)(wid*64)*8);       \
    GLD_LDS16(kh + (size_t)(256 + wid*64 + lane)*8, kbuf0 + (size_t)(256 + wid*64)*8); \
    _Pragma("unroll 2")                                                        \
    for (int nt = 0; nt < 16; ++nt) {                                          \
        _Float16* kcur = (nt & 1) ? kbuf1 : kbuf0;                             \
        _Float16* knxt = (nt & 1) ? kbuf0 : kbuf1;                             \
        if (nt < 15) {                                                         \
            const _Float16* src = kh + (size_t)(nt+1)*4096;                    \
            GLD_LDS16(src + (size_t)(wid*64 + lane)*8,       knxt + (size_t)(wid*64)*8);       \
            GLD_LDS16(src + (size_t)(256 + wid*64 + lane)*8, knxt + (size_t)(256 + wid*64)*8); \
            WAIT_VM(2);                                                        \
        } else {                                                               \
            WAIT_VM(0);                                                        \
        }                                                                      \
        __builtin_amdgcn_s_barrier();                                          \
        f32x16 acc;                                                            \
        _Pragma("unroll")                                                      \
        for (int r = 0; r < 16; ++r) acc[r] = 0.f;                             \
        _Pragma("unroll")                                                      \
        for (int ds = 0; ds < 8; ++ds) {                                       \
            f16x8 kf = *(const f16x8*)(kcur + (size_t)(ds*64 + lane)*8);       \
            acc = __builtin_amdgcn_mfma_f32_32x32x16_f16(kf, qf[ds], acc, 0, 0, 0); \
        }                                                                      \
        TOP2_UPDATE(acc, nt)                                                   \
        __builtin_amdgcn_s_barrier();                                          \
    }

#define MERGE32()                                                              \
    float o1 = __shfl_xor(v1, 32), o2 = __shfl_xor(v2, 32);                    \
    int oi = __shfl_xor(i1, 32);                                               \
    bool sw = (o1 > v1) || (o1 == v1 && oi < i1);                              \
    const float V1 = sw ? o1 : v1;                                             \
    int idx = sw ? oi : i1;                                                    \
    const float V2 = fmaxf(fminf(v1, o1), fmaxf(v2, o2));

#define REPAIR()                                                               \
    unsigned long long mf = __ballot(V1 - V2 < TAU) & 0xffffffffull;           \
    float* qb = qbuf + wid * 128;                                              \
    while (mf) {                                                               \
        int src = (int)__builtin_ctzll(mf); mf &= mf - 1;                      \
        int rl = l0w + src;                                                    \
        qb[lane]      = SCALE * xb[(size_t)lane*L_ + rl];                      \
        qb[lane + 64] = SCALE * xb[(size_t)(lane+64)*L_ + rl];                 \
        __builtin_amdgcn_wave_barrier();                                       \
        WAIT_LGKM;                                                             \
        float accs[8];                                                         \
        _Pragma("unroll")                                                      \
        for (int u = 0; u < 8; ++u) accs[u] = 0.f;                             \
        const float* kr = K32 + ((size_t)(h*NC_ + lane))*D_;                   \
        for (int d4 = 0; d4 < 32; ++d4) {                                      \
            float qd0 = qb[d4*4+0], qd1 = qb[d4*4+1], qd2 = qb[d4*4+2], qd3 = qb[d4*4+3]; \
            _Pragma("unroll")                                                  \
            for (int u = 0; u < 8; ++u) {                                      \
                f32x4 kk = *(const f32x4*)(kr + (size_t)u*64*D_ + d4*4);       \
                accs[u] = fmaf(qd0, kk[0], accs[u]);                           \
                accs[u] = fmaf(qd1, kk[1], accs[u]);                           \
                accs[u] = fmaf(qd2, kk[2], accs[u]);                           \
                accs[u] = fmaf(qd3, kk[3], accs[u]);                           \
            }                                                                  \
        }                                                                      \
        float bv = -INFINITY; int bn = 0;                                      \
        _Pragma("unroll")                                                      \
        for (int u = 0; u < 8; ++u) {                                          \
            if (accs[u] > bv) { bv = accs[u]; bn = lane + (u << 6); }          \
        }                                                                      \
        _Pragma("unroll")                                                      \
        for (int m = 1; m < 64; m <<= 1) {                                     \
            float ov = __shfl_xor(bv, m);                                      \
            int on = __shfl_xor(bn, m);                                        \
            if (ov > bv || (ov == bv && on < bn)) { bv = ov; bn = on; }        \
        }                                                                      \
        if (lane == src) idx = bn;                                             \
        __builtin_amdgcn_wave_barrier();                                       \
    }                                                                          \
    idx = __shfl(idx, colL);

#define EPILOGUE(OUTP, IDXP)                                                   \
    const int myl = l0w + colL;                                                \
    if (!hi) (IDXP)[((size_t)(b*H_ + h))*L_ + myl] = (float)idx;               \
    const f32x4* vrow = (const f32x4*)(V + ((size_t)(h*NC_ + idx))*D_);        \
    float* ob = (OUTP) + ((size_t)(b*1024 + h*128 + hi*64))*L_ + myl;          \
    _Pragma("unroll")                                                          \
    for (int p = 0; p < 16; ++p) {                                             \
        f32x4 vv = vrow[hi*16 + p];                                            \
        ob[(size_t)(p*4+0)*L_] = vv[0];                                        \
        ob[(size_t)(p*4+1)*L_] = vv[1];                                        \
        ob[(size_t)(p*4+2)*L_] = vv[2];                                        \
        ob[(size_t)(p*4+3)*L_] = vv[3];                                        \
    }

// ---------------------------------------------------------------------------
// PROBE A: q phase only. Checksum -> out region (overwritten by C/D later).
// ---------------------------------------------------------------------------
__global__ __launch_bounds__(256, 4) void abl_q(
    const float* __restrict__ x, float* __restrict__ out)
{
    __shared__ __align__(16) char smem[32768 + 2048];
    DECODE_IDS();
    f16x8 qf[8];
    QPHASE_ARR()
    float cs = 0.f;
    #pragma unroll
    for (int i = 0; i < 8; ++i)
        #pragma unroll
        for (int j = 0; j < 8; ++j) cs += (float)qf[i][j];
    out[(size_t)bid * 256 + t] = cs;
}

// ---------------------------------------------------------------------------
// PROBE B: q + K loop + merge (no repair, no gather). V1/V2/idx -> out region.
// ---------------------------------------------------------------------------
__global__ __launch_bounds__(256, 4) void abl_qk(
    const float* __restrict__ x, const _Float16* __restrict__ K16f,
    float* __restrict__ out, float* __restrict__ idxs)
{
    __shared__ __align__(16) char smem[32768 + 2048];
    _Float16* kbuf0 = (_Float16*)smem;
    _Float16* kbuf1 = (_Float16*)(smem + 8192);
    DECODE_IDS();
    f16x8 qf[8];
    QPHASE_ARR()
    __syncthreads();
    const _Float16* kh = K16f + ((size_t)h << 16);
    float v1 = -INFINITY, v2 = -INFINITY;
    int i1 = 0;
    KLOOP_ARR()
    MERGE32()
    const int myl = l0w + colL;
    if (!hi) {
        out [((size_t)(b*H_ + h))*L_ + myl] = V1 + 0.001f * V2;  // keep v2 chain live
        idxs[((size_t)(b*H_ + h))*L_ + myl] = (float)idx;
    }
}

// ---------------------------------------------------------------------------
// PROBE E: epilogue only (hashed fake idx, identical store pattern) -> out.
// ---------------------------------------------------------------------------
__global__ __launch_bounds__(256, 4) void abl_epi(
    const float* __restrict__ V, float* __restrict__ out, float* __restrict__ idxs)
{
    const float* x = nullptr; (void)x;
    const int t = threadIdx.x;
    const int wid = t >> 6, lane = t & 63;
    const int bid = blockIdx.x;
    const int h  = bid & 7;
    const int rr_ = bid >> 3;
    const int lx = rr_ & 31, b = rr_ >> 5;
    const int l0w = lx * 128 + wid * 32;
    const int colL = lane & 31;
    const int hi = lane >> 5;
    const int myl = l0w + colL;
    int idx = (int)(((unsigned)(myl + h * 131 + b * 977) * 2654435761u) >> 23) & 511;
    if (!hi) idxs[((size_t)(b*H_ + h))*L_ + myl] = (float)idx;
    const f32x4* vrow = (const f32x4*)(V + ((size_t)(h*NC_ + idx))*D_);
    float* ob = out + ((size_t)(b*1024 + h*128 + hi*64))*L_ + myl;
    #pragma unroll
    for (int p = 0; p < 16; ++p) {
        f32x4 vv = vrow[hi*16 + p];
        ob[(size_t)(p*4+0)*L_] = vv[0];
        ob[(size_t)(p*4+1)*L_] = vv[1];
        ob[(size_t)(p*4+2)*L_] = vv[2];
        ob[(size_t)(p*4+3)*L_] = vv[3];
    }
}

// ---------------------------------------------------------------------------
// C: full kernel, round-5 verbatim (array qf). Writes real outputs.
// ---------------------------------------------------------------------------
__global__ __launch_bounds__(256, 4) void attn_main(
    const float* __restrict__ x, const _Float16* __restrict__ K16f,
    const float* __restrict__ K32, const float* __restrict__ V,
    float* __restrict__ out, float* __restrict__ idxf)
{
    __shared__ __align__(16) char smem[32768 + 2048];
    _Float16* kbuf0 = (_Float16*)smem;
    _Float16* kbuf1 = (_Float16*)(smem + 8192);
    float*    qbuf  = (float*)(smem + 16384);
    DECODE_IDS();
    f16x8 qf[8];
    QPHASE_ARR()
    __syncthreads();
    const _Float16* kh = K16f + ((size_t)h << 16);
    float v1 = -INFINITY, v2 = -INFINITY;
    int i1 = 0;
    KLOOP_ARR()
    MERGE32()
    REPAIR()
    EPILOGUE(out, idxf)
}

// ---------------------------------------------------------------------------
// D: identical to C except qf de-arrayed into 8 named registers (spill test).
// Writes the same correct outputs (runs after C).
// ---------------------------------------------------------------------------
__global__ __launch_bounds__(256, 4) void attn_main_d(
    const float* __restrict__ x, const _Float16* __restrict__ K16f,
    const float* __restrict__ K32, const float* __restrict__ V,
    float* __restrict__ out, float* __restrict__ idxf)
{
    __shared__ __align__(16) char smem[32768 + 2048];
    _Float16* kbuf0 = (_Float16*)smem;
    _Float16* kbuf1 = (_Float16*)(smem + 8192);
    float*    qbuf  = (float*)(smem + 16384);
    DECODE_IDS();
    f16x8 qf0, qf1, qf2, qf3, qf4, qf5, qf6, qf7;
    {
        float* qs0 = (float*)(smem + wid * 8192);
        float* qs1 = (float*)(smem + wid * 8192 + 4096);
        QSTAGE(0, qs0)
        QSTAGE(1, qs1)
        WAIT_VM(4); QREAD1(0, qs0, 0, qf0) QREAD1(0, qs0, 1, qf1)
        WAIT_LGKM;  QSTAGE(2, qs0)
        WAIT_VM(4); QREAD1(1, qs1, 0, qf2) QREAD1(1, qs1, 1, qf3)
        WAIT_LGKM;  QSTAGE(3, qs1)
        WAIT_VM(4); QREAD1(2, qs0, 0, qf4) QREAD1(2, qs0, 1, qf5)
        WAIT_VM(0); QREAD1(3, qs1, 0, qf6) QREAD1(3, qs1, 1, qf7)
    }
    __syncthreads();
    const _Float16* kh = K16f + ((size_t)h << 16);
    float v1 = -INFINITY, v2 = -INFINITY;
    int i1 = 0;

    GLD_LDS16(kh + (size_t)(wid*64 + lane)*8,       kbuf0 + (size_t)(wid*64)*8);
    GLD_LDS16(kh + (size_t)(256 + wid*64 + lane)*8, kbuf0 + (size_t)(256 + wid*64)*8);
    #pragma unroll 2
    for (int nt = 0; nt < 16; ++nt) {
        _Float16* kcur = (nt & 1) ? kbuf1 : kbuf0;
        _Float16* knxt = (nt & 1) ? kbuf0 : kbuf1;
        if (nt < 15) {
            const _Float16* src = kh + (size_t)(nt+1)*4096;
            GLD_LDS16(src + (size_t)(wid*64 + lane)*8,       knxt + (size_t)(wid*64)*8);
            GLD_LDS16(src + (size_t)(256 + wid*64 + lane)*8, knxt + (size_t)(256 + wid*64)*8);
            WAIT_VM(2);
        } else {
            WAIT_VM(0);
        }
        __builtin_amdgcn_s_barrier();
        f32x16 acc;
        #pragma unroll
        for (int r = 0; r < 16; ++r) acc[r] = 0.f;
        #define KMFMA(DS, QF)                                                  \
          { f16x8 kf = *(const f16x8*)(kcur + (size_t)((DS)*64 + lane)*8);     \
            acc = __builtin_amdgcn_mfma_f32_32x32x16_f16(kf, QF, acc, 0, 0, 0); }
        KMFMA(0, qf0) KMFMA(1, qf1) KMFMA(2, qf2) KMFMA(3, qf3)
        KMFMA(4, qf4) KMFMA(5, qf5) KMFMA(6, qf6) KMFMA(7, qf7)
        #undef KMFMA
        TOP2_UPDATE(acc, nt)
        __builtin_amdgcn_s_barrier();
    }
    MERGE32()
    REPAIR()
    EPILOGUE(out, idxf)
}

extern "C" void kernel_launch(void* const* d_in, const int* in_sizes, int n_in,
                              void* d_out, int out_size, void* d_ws, size_t ws_size,
                              hipStream_t stream)
{
    const float* x     = (const float*)d_in[0];
    const float* codes = (const float*)d_in[1];
    const float* Wk    = (const float*)d_in[2];
    const float* Wv    = (const float*)d_in[3];

    float* out  = (float*)d_out;
    float* idxf = out + (size_t)B_ * H_ * D_ * L_;

    _Float16* K16f = (_Float16*)d_ws;                        // 1 MB
    float*    K32  = (float*)((char*)d_ws + (1u << 20));     // 2 MB
    float*    Vf   = (float*)((char*)d_ws + (3u << 20));     // 2 MB

    kv_pre<<<dim3(64, 8), 256, 0, stream>>>(codes, Wk, Wv, K16f, K32, Vf);
    // --- ablation probes (all outputs land in regions C/D rewrite) ---
    abl_q  <<<dim3(1024), 256, 0, stream>>>(x, out);
    abl_qk <<<dim3(1024), 256, 0, stream>>>(x, K16f, out, idxf);
    abl_epi<<<dim3(1024), 256, 0, stream>>>(Vf, out, idxf);
    // --- real kernels (D overwrites C with identical values) ---
    attn_main  <<<dim3(1024), 256, 0, stream>>>(x, K16f, K32, Vf, out, idxf);
    attn_main_d<<<dim3(1024), 256, 0, stream>>>(x, K16f, K32, Vf, out, idxf);
}

// Round 8
// 91.770 us; speedup vs baseline: 3.8779x; 3.8779x over previous
//
#include <hip/hip_runtime.h>
#include <cstdint>

#define L_ 4096
#define NC_ 512
#define CD_ 256
#define H_ 8
#define D_ 128
#define B_ 4
#define SCALE 0.08838834764831845f
#define TAU 3.0e-3f

typedef _Float16 f16x8 __attribute__((ext_vector_type(8)));
typedef _Float16 f16x4 __attribute__((ext_vector_type(4)));
typedef float f32x16 __attribute__((ext_vector_type(16)));
typedef float f32x4 __attribute__((ext_vector_type(4)));

// ---------------------------------------------------------------------------
// Kernel A (verbatim, verified): K16f fp16 fragment-major, K32/V fp32 row-major.
// ---------------------------------------------------------------------------
__global__ __launch_bounds__(256) void kv_pre(
    const float* __restrict__ codes, const float* __restrict__ Wk,
    const float* __restrict__ Wv, _Float16* __restrict__ K16f,
    float* __restrict__ K32, float* __restrict__ V)
{
    __shared__ float clds[8][256];
    const int t = threadIdx.x, h = blockIdx.y, n0 = blockIdx.x * 8;
    {
        const float4* cs = (const float4*)(codes + (size_t)n0 * CD_);
        float4* cd = (float4*)&clds[0][0];
        cd[t] = cs[t]; cd[t + 256] = cs[t + 256];
    }
    __syncthreads();
    const int nl = t >> 5, dq = t & 31, d0 = dq * 4, n = n0 + nl;
    float ak0=0,ak1=0,ak2=0,ak3=0, av0=0,av1=0,av2=0,av3=0;
    const float4* wk4 = (const float4*)Wk;
    const float4* wv4 = (const float4*)Wv;
    for (int c = 0; c < CD_; c += 4) {
        float4 cv = *(const float4*)&clds[nl][c];
        #pragma unroll
        for (int u = 0; u < 4; ++u) {
            float cu = (u==0)?cv.x:(u==1)?cv.y:(u==2)?cv.z:cv.w;
            float4 wk = wk4[((size_t)(c+u)*H_ + h)*32 + dq];
            float4 wv = wv4[((size_t)(c+u)*H_ + h)*32 + dq];
            ak0 = fmaf(cu, wk.x, ak0); ak1 = fmaf(cu, wk.y, ak1);
            ak2 = fmaf(cu, wk.z, ak2); ak3 = fmaf(cu, wk.w, ak3);
            av0 = fmaf(cu, wv.x, av0); av1 = fmaf(cu, wv.y, av1);
            av2 = fmaf(cu, wv.z, av2); av3 = fmaf(cu, wv.w, av3);
        }
    }
    const size_t r32 = ((size_t)(h*NC_ + n))*D_ + d0;
    float4 sk; sk.x=ak0; sk.y=ak1; sk.z=ak2; sk.w=ak3;
    float4 sv; sv.x=av0; sv.y=av1; sv.z=av2; sv.w=av3;
    *(float4*)(K32 + r32) = sk;
    *(float4*)(V   + r32) = sv;
    f16x4 hk; hk[0]=(_Float16)ak0; hk[1]=(_Float16)ak1; hk[2]=(_Float16)ak2; hk[3]=(_Float16)ak3;
    const size_t a16 = ((size_t)((h*16 + (n>>5))*8 + (d0>>4))*64
                        + ((n&31) + ((d0>>3)&1)*32))*8 + (d0&7);
    *(f16x4*)(K16f + a16) = hk;
}

// ---------------------------------------------------------------------------
// Kernel B: drain-conservative sync (no counted vmcnt anywhere) + two-tier
// repair. q via DMA LDS transpose with full WAIT_VM(0) drains; K tiles
// double-buffered with __syncthreads per tile (round-4-proven).
// ---------------------------------------------------------------------------
#define GLD_LDS16(GP, LP)                                                      \
  __builtin_amdgcn_global_load_lds(                                            \
      (const __attribute__((address_space(1))) void*)(GP),                     \
      (__attribute__((address_space(3))) void*)(LP), 16, 0, 0)

#define WAIT_VM0    asm volatile("s_waitcnt vmcnt(0)" ::: "memory")
#define WAIT_LGKM   asm volatile("s_waitcnt lgkmcnt(0)" ::: "memory")

#define QSTAGE(RD, QS)                                                         \
  _Pragma("unroll")                                                            \
  for (int i_ = 0; i_ < 4; ++i_) {                                             \
    const float* sp_ = xb + (size_t)((RD)*32 + i_*8 + (lane>>3))*L_            \
                          + l0w + (lane&7)*4;                                  \
    GLD_LDS16(sp_, (char*)(QS) + i_*1024);                                     \
  }

#define QREAD(RD, QS)                                                          \
  _Pragma("unroll")                                                            \
  for (int p_ = 0; p_ < 2; ++p_) {                                             \
    f16x8 tmp_;                                                                \
    _Pragma("unroll")                                                          \
    for (int j_ = 0; j_ < 8; ++j_)                                             \
      tmp_[j_] = (_Float16)(SCALE * (QS)[(p_*16 + hi*8 + j_)*32 + colL]);      \
    qf[(RD)*2 + p_] = tmp_;                                                    \
  }

__global__ __launch_bounds__(256, 4) void attn_main(
    const float* __restrict__ x, const _Float16* __restrict__ K16f,
    const float* __restrict__ K32, const float* __restrict__ V,
    float* __restrict__ out, float* __restrict__ idxf)
{
    __shared__ __align__(16) char smem[32768 + 2048];
    _Float16* kbuf0 = (_Float16*)smem;            // 8 KB
    _Float16* kbuf1 = (_Float16*)(smem + 8192);   // 8 KB
    float*    qbuf  = (float*)(smem + 32768);     // 4 x 128 floats (repair)

    const int t = threadIdx.x;
    const int wid = t >> 6, lane = t & 63;
    const int bid = blockIdx.x;
    const int h  = bid & 7;              // head-per-XCD affinity
    const int rr_ = bid >> 3;
    const int lx = rr_ & 31, b = rr_ >> 5;
    const int l0w = lx * 128 + wid * 32;

    const float* xb = x + ((size_t)(b*1024 + h*128)) * L_;
    const int colL = lane & 31;
    const int hi = lane >> 5;
    const int laneN4 = hi * 4;

    // ======= q phase: per-wave DMA transpose, full drains (robust) =========
    float* qs0 = (float*)(smem + wid * 8192);
    float* qs1 = (float*)(smem + wid * 8192 + 4096);
    f16x8 qf[8];
    QSTAGE(0, qs0)
    QSTAGE(1, qs1)
    WAIT_VM0;             // rounds 0+1 fully landed
    QREAD(0, qs0)
    QREAD(1, qs1)
    WAIT_LGKM;            // reads consumed before overwrite
    QSTAGE(2, qs0)
    QSTAGE(3, qs1)
    WAIT_VM0;             // rounds 2+3 fully landed
    QREAD(2, qs0)
    QREAD(3, qs1)
    __syncthreads();      // qstage dead; reuse LDS as kbuf

    // ======= K loop: drain-per-tile double buffer (round-4-proven) =========
    const _Float16* kh = K16f + ((size_t)h << 16);

    GLD_LDS16(kh + (size_t)(wid*64 + lane)*8,       kbuf0 + (size_t)(wid*64)*8);
    GLD_LDS16(kh + (size_t)(256 + wid*64 + lane)*8, kbuf0 + (size_t)(256 + wid*64)*8);

    float v1 = -INFINITY, v2 = -INFINITY, v3 = -INFINITY;
    int i1 = 0, i2 = 0;

    __syncthreads();      // tile 0 staged (syncthreads drains vmcnt)

    for (int nt = 0; nt < 16; ++nt) {
        _Float16* kcur = (nt & 1) ? kbuf1 : kbuf0;
        _Float16* knxt = (nt & 1) ? kbuf0 : kbuf1;
        if (nt < 15) {    // prefetch next tile; landing guaranteed by the
                          // loop-end __syncthreads (full drain)
            const _Float16* src = kh + (size_t)(nt+1)*4096;
            GLD_LDS16(src + (size_t)(wid*64 + lane)*8,       knxt + (size_t)(wid*64)*8);
            GLD_LDS16(src + (size_t)(256 + wid*64 + lane)*8, knxt + (size_t)(256 + wid*64)*8);
        }
        f32x16 acc;
        #pragma unroll
        for (int r = 0; r < 16; ++r) acc[r] = 0.f;
        #pragma unroll
        for (int ds = 0; ds < 8; ++ds) {
            f16x8 kf = *(const f16x8*)(kcur + (size_t)(ds*64 + lane)*8);
            acc = __builtin_amdgcn_mfma_f32_32x32x16_f16(kf, qf[ds], acc, 0, 0, 0);
        }
        // top-3 values + top-2 indices (round-2 verified update)
        const int nb = nt*32 + laneN4;
        #pragma unroll
        for (int r = 0; r < 16; ++r) {
            const int n = nb + (r & 3) + ((r >> 2) << 3);
            float v = acc[r];
            bool gt1 = v > v1;
            bool gt2 = v > v2;
            i2 = gt1 ? i1 : (gt2 ? n : i2);
            i1 = gt1 ? n  : i1;
            v3 = fmaxf(v3, fminf(v2, v));
            v2 = fmaxf(v2, fminf(v1, v));
            v1 = fmaxf(v1, v);
        }
        __syncthreads();  // drains prefetch (vmcnt 0) + readers-done ordering
    }

    // ---- merge lane^32 halves: top-3 values + top-2 indices (round-2 verified)
    float ov1 = __shfl_xor(v1, 32), ov2 = __shfl_xor(v2, 32), ov3 = __shfl_xor(v3, 32);
    int oi1 = __shfl_xor(i1, 32), oi2 = __shfl_xor(i2, 32);
    bool sw = (ov1 > v1) || (ov1 == v1 && oi1 < i1);
    float a1 = sw ? ov1 : v1;  int ai1 = sw ? oi1 : i1;
    float b1 = sw ? v1 : ov1;  int bi1 = sw ? i1 : oi1;
    float a2 = sw ? ov2 : v2;  int ai2 = sw ? oi2 : i2;
    float b2 = sw ? v2 : ov2;
    float a3 = sw ? ov3 : v3;
    bool sec = (b1 > a2) || (b1 == a2 && bi1 < ai2);
    const float V1 = a1;             const int I1 = ai1;
    const float V2 = sec ? b1 : a2;  const int I2 = sec ? bi1 : ai2;
    const float V3 = sec ? fmaxf(a2, b2) : fmaxf(a3, b1);
    int idx = I1;

    const bool cheap = (V1 - V2 < TAU) && (V1 - V3 >= TAU);
    const bool full  = (V1 - V3 < TAU);

    // ---- tier 1: cheap repair — exact fp32 dots for the two candidates only
    unsigned long long mc = __ballot(cheap) & 0xffffffffull;
    while (mc) {
        int src = (int)__builtin_ctzll(mc); mc &= mc - 1;
        int rl = l0w + src;
        int ra = __shfl(I1, src);
        int rb = __shfl(I2, src);
        int n = hi ? rb : ra;
        f32x4 kk = *(const f32x4*)(K32 + ((size_t)(h*NC_ + n))*D_ + colL*4);
        int dd = colL * 4;
        float q0 = SCALE * xb[(size_t)(dd+0)*L_ + rl];
        float q1 = SCALE * xb[(size_t)(dd+1)*L_ + rl];
        float q2 = SCALE * xb[(size_t)(dd+2)*L_ + rl];
        float q3 = SCALE * xb[(size_t)(dd+3)*L_ + rl];
        float p = q0 * kk[0];
        p = fmaf(q1, kk[1], p); p = fmaf(q2, kk[2], p); p = fmaf(q3, kk[3], p);
        #pragma unroll
        for (int m = 1; m < 32; m <<= 1) p += __shfl_xor(p, m);
        float va = __shfl(p, 0);
        float vb = __shfl(p, 32);
        bool takeB = (vb > va) || (vb == va && rb < ra);
        int win = takeB ? rb : ra;
        if (lane == src) idx = win;
    }

    // ---- tier 2: full exact rescan (double-ties only; rare)
    unsigned long long mf2 = __ballot(full) & 0xffffffffull;
    float* qb = qbuf + wid * 128;
    while (mf2) {
        int src = (int)__builtin_ctzll(mf2); mf2 &= mf2 - 1;
        int rl = l0w + src;
        qb[lane]      = SCALE * xb[(size_t)lane*L_ + rl];
        qb[lane + 64] = SCALE * xb[(size_t)(lane+64)*L_ + rl];
        __builtin_amdgcn_wave_barrier();
        WAIT_LGKM;
        float accs[8];
        #pragma unroll
        for (int u = 0; u < 8; ++u) accs[u] = 0.f;
        const float* kr = K32 + ((size_t)(h*NC_ + lane))*D_;
        for (int d4 = 0; d4 < 32; ++d4) {
            float qd0 = qb[d4*4+0], qd1 = qb[d4*4+1], qd2 = qb[d4*4+2], qd3 = qb[d4*4+3];
            #pragma unroll
            for (int u = 0; u < 8; ++u) {
                f32x4 kk = *(const f32x4*)(kr + (size_t)u*64*D_ + d4*4);
                accs[u] = fmaf(qd0, kk[0], accs[u]);
                accs[u] = fmaf(qd1, kk[1], accs[u]);
                accs[u] = fmaf(qd2, kk[2], accs[u]);
                accs[u] = fmaf(qd3, kk[3], accs[u]);
            }
        }
        float bv = -INFINITY; int bn = 0;
        #pragma unroll
        for (int u = 0; u < 8; ++u) {
            if (accs[u] > bv) { bv = accs[u]; bn = lane + (u << 6); }
        }
        #pragma unroll
        for (int m = 1; m < 64; m <<= 1) {
            float ov = __shfl_xor(bv, m);
            int on = __shfl_xor(bn, m);
            if (ov > bv || (ov == bv && on < bn)) { bv = ov; bn = on; }
        }
        if (lane == src) idx = bn;
        __builtin_amdgcn_wave_barrier();
    }
    idx = __shfl(idx, colL);   // broadcast repaired idx to the hi-half lane

    // ---- outputs: idx (as float, lanes 0-31) + fused V gather (d split by hi)
    const int myl = l0w + colL;
    if (!hi) idxf[((size_t)(b*H_ + h))*L_ + myl] = (float)idx;
    const f32x4* vrow = (const f32x4*)(V + ((size_t)(h*NC_ + idx))*D_);
    float* ob = out + ((size_t)(b*1024 + h*128 + hi*64))*L_ + myl;
    #pragma unroll
    for (int p = 0; p < 16; ++p) {
        f32x4 vv = vrow[hi*16 + p];
        ob[(size_t)(p*4+0)*L_] = vv[0];
        ob[(size_t)(p*4+1)*L_] = vv[1];
        ob[(size_t)(p*4+2)*L_] = vv[2];
        ob[(size_t)(p*4+3)*L_] = vv[3];
    }
}

extern "C" void kernel_launch(void* const* d_in, const int* in_sizes, int n_in,
                              void* d_out, int out_size, void* d_ws, size_t ws_size,
                              hipStream_t stream)
{
    const float* x     = (const float*)d_in[0];
    const float* codes = (const float*)d_in[1];
    const float* Wk    = (const float*)d_in[2];
    const float* Wv    = (const float*)d_in[3];

    float* out  = (float*)d_out;
    float* idxf = out + (size_t)B_ * H_ * D_ * L_;

    _Float16* K16f = (_Float16*)d_ws;                        // 1 MB
    float*    K32  = (float*)((char*)d_ws + (1u << 20));     // 2 MB
    float*    Vf   = (float*)((char*)d_ws + (3u << 20));     // 2 MB

    kv_pre<<<dim3(64, 8), 256, 0, stream>>>(codes, Wk, Wv, K16f, K32, Vf);
    attn_main<<<dim3(1024), 256, 0, stream>>>(x, K16f, K32, Vf, out, idxf);
}